// Round 14
// baseline (405.443 us; speedup 1.0000x reference)
//
#include <hip/hip_runtime.h>
#include <hip/hip_bf16.h>
#include <math.h>

// StackedGCN: N=100000, E=1600000, 128 -> 128 -> 128 -> 64, fp32 in/out.
// bf16 activations, fp32 accumulation, MFMA bf16 GEMMs, dinv prescaled in
// GEMM epilogue (aggregation = pure sum). CSR build: single-kernel bump
// allocation into PADDED bucket segments + LDS counting sort.
// agg128 is at its structural floor (~64us: 190MB = 8 XCD x 25.6MB fill at
// ~10-12 B/cyc/CU service). DIAGNOSTIC this round: each agg128 dispatch is
// split into two half-node-range dispatches (~32us) so the rocprof top-5
// exposes the remaining kernels' ranking (agg_softmax/scatter/bucket/gemm).
#define NN 100000
#define EE 1600000
#define NB2 782     // dst buckets: dst>>7 -> 128 nodes per bucket
#define BN 128      // nodes per bucket
#define NPART 512   // scatter_bump blocks
#define CAP 2560    // padded segment capacity (mean 2048, sd ~45 -> +11 sigma)

typedef __attribute__((ext_vector_type(8))) short short8;
typedef __attribute__((ext_vector_type(4))) float f32x4;
typedef __attribute__((ext_vector_type(2))) float f32x2;

__device__ inline unsigned short f2bf(float x) {
    unsigned u = __float_as_uint(x);
    unsigned r = u + 0x7FFFu + ((u >> 16) & 1u);
    return (unsigned short)(r >> 16);
}
__device__ inline unsigned pack2bf(float a, float b) {
    return (unsigned)f2bf(a) | ((unsigned)f2bf(b) << 16);
}
__device__ inline f32x2 bf2f2(unsigned u) {
    f32x2 r;
    r.x = __uint_as_float(u << 16);
    r.y = __uint_as_float(u & 0xFFFF0000u);
    return r;
}

// ---------------- weight prep (+ bcount zero) ----------------

__global__ void prep_weights(const float* __restrict__ W0, const float* __restrict__ W1,
                             const float* __restrict__ W2, unsigned short* __restrict__ Wt0,
                             unsigned short* __restrict__ Wt1, unsigned short* __restrict__ Wt2,
                             int* __restrict__ bcount) {
    int g = blockIdx.x * 256 + threadIdx.x;
    if (g < NB2) bcount[g] = 0;
    if (g < 16384) {
        int n = g >> 7, k = g & 127;
        Wt0[g] = f2bf(W0[k * 128 + n]);
    } else if (g < 32768) {
        int i = g - 16384;
        int n = i >> 7, k = i & 127;
        Wt1[i] = f2bf(W1[k * 128 + n]);
    } else if (g < 40960) {
        int i = g - 32768;
        int n = i >> 7, k = i & 127;
        Wt2[i] = f2bf(W2[k * 64 + n]);
    }
}

// ---------------- CSR build ----------------

__global__ __launch_bounds__(256) void scatter_bump(const int* __restrict__ src,
                                                    const int* __restrict__ dst,
                                                    int* __restrict__ bcount,
                                                    int* __restrict__ P, int e) {
    __shared__ int cnt[NB2];
    __shared__ int basep[NB2];
    __shared__ int cur[NB2];
    int t = threadIdx.x;
    for (int i = t; i < NB2; i += 256) { cnt[i] = 0; cur[i] = 0; }
    __syncthreads();
    int chunk = (e + NPART - 1) / NPART;
    int b0 = blockIdx.x * chunk, b1 = min(e, b0 + chunk);
    for (int i = b0 + t; i < b1; i += 256)
        atomicAdd(&cnt[dst[i] >> 7], 1);
    __syncthreads();
    for (int i = t; i < NB2; i += 256) {
        int c = cnt[i];
        basep[i] = c ? atomicAdd(&bcount[i], c) : 0;
    }
    __syncthreads();
    for (int i = b0 + t; i < b1; i += 256) {  // second read is L2-hot
        int d = dst[i];
        int b = d >> 7;
        int p = basep[b] + atomicAdd(&cur[b], 1);
        P[(size_t)b * CAP + p] = (src[i] << 7) | (d & 127);  // src<2^17: 24 bits
    }
}

__global__ __launch_bounds__(256) void bucket_build(const int* __restrict__ P,
                                                    const int* __restrict__ bcount,
                                                    int2* __restrict__ offs2,
                                                    float* __restrict__ dinv,
                                                    int* __restrict__ csr, int n) {
    __shared__ int cnt[BN];
    __shared__ int sc[BN];
    __shared__ int cur[BN];
    __shared__ int stage[CAP];
    int b = blockIdx.x, t = threadIdx.x;
    int base = b * CAP;
    int count = bcount[b];
    if (t < BN) cnt[t] = 0;
    __syncthreads();
    for (int i = t; i < count; i += 256)
        atomicAdd(&cnt[P[base + i] & 127], 1);
    __syncthreads();
    int v = 0;
    if (t < BN) {
        v = cnt[t];
        sc[t] = v;
    }
    for (int d = 1; d < BN; d <<= 1) {
        __syncthreads();
        int x = (t < BN && t >= d) ? sc[t - d] : 0;
        __syncthreads();
        if (t < BN) sc[t] += x;
    }
    __syncthreads();
    if (t < BN) {
        int myoff = sc[t] - v;
        int node = b * BN + t;
        if (node < n) {
            offs2[node] = make_int2(base + myoff, base + myoff + v);
            dinv[node] = 1.0f / sqrtf((float)(v + 1));  // +1 self-loop
        }
        cur[t] = myoff;
    }
    __syncthreads();
    for (int i = t; i < count; i += 256) {  // second read L2-hot
        int pe = P[base + i];
        int p = atomicAdd(&cur[pe & 127], 1);
        stage[p] = ((unsigned)pe) >> 7;     // p < count <= CAP always
    }
    __syncthreads();
    for (int i = t; i < count; i += 256) csr[base + i] = stage[i];
}

// ---------------- MFMA GEMM + dinv-prescale epilogue ----------------
template <int DOUT, bool A_IS_F32>
__global__ __launch_bounds__(256) void gemm_mfma(const void* __restrict__ Aptr,
                                                 const unsigned short* __restrict__ Wt,
                                                 const float* __restrict__ dinv,
                                                 unsigned short* __restrict__ Y, int nrows) {
    constexpr int KP = 136;
    constexpr int NT = DOUT / 16;
    __shared__ unsigned short sA[128 * KP];
    __shared__ unsigned short sB[DOUT * KP];
    const int row0 = blockIdx.x * 128;
    const int tid = threadIdx.x;

    for (int i = tid; i < DOUT * 16; i += 256) {
        int n = i >> 4, c = (i & 15) * 8;
        uint4 v = *(const uint4*)(Wt + n * 128 + c);
        *(uint4*)(&sB[n * KP + c]) = v;
    }
    if (A_IS_F32) {
        const float* A = (const float*)Aptr;
        for (int i = tid; i < 128 * 32; i += 256) {
            int r = i >> 5, c = (i & 31) * 4;
            float4 v = make_float4(0.f, 0.f, 0.f, 0.f);
            if (row0 + r < nrows) v = *(const float4*)(A + (size_t)(row0 + r) * 128 + c);
            uint2 o;
            o.x = pack2bf(v.x, v.y);
            o.y = pack2bf(v.z, v.w);
            *(uint2*)(&sA[r * KP + c]) = o;
        }
    } else {
        const unsigned short* A = (const unsigned short*)Aptr;
        for (int i = tid; i < 128 * 16; i += 256) {
            int r = i >> 4, c = (i & 15) * 8;
            uint4 v = make_uint4(0u, 0u, 0u, 0u);
            if (row0 + r < nrows) v = *(const uint4*)(A + (size_t)(row0 + r) * 128 + c);
            *(uint4*)(&sA[r * KP + c]) = v;
        }
    }
    __syncthreads();

    const int wave = tid >> 6;
    const int lane = tid & 63;
    const int m0 = lane & 15;
    const int kq = (lane >> 4) * 8;

    f32x4 acc[2][NT];
#pragma unroll
    for (int rt = 0; rt < 2; ++rt)
#pragma unroll
        for (int t = 0; t < NT; ++t) acc[rt][t] = (f32x4){0.f, 0.f, 0.f, 0.f};

#pragma unroll
    for (int k0 = 0; k0 < 128; k0 += 32) {
        short8 a0 = *(const short8*)(&sA[(wave * 32 + m0) * KP + k0 + kq]);
        short8 a1 = *(const short8*)(&sA[(wave * 32 + 16 + m0) * KP + k0 + kq]);
#pragma unroll
        for (int t = 0; t < NT; ++t) {
            short8 b = *(const short8*)(&sB[(t * 16 + m0) * KP + k0 + kq]);
            acc[0][t] = __builtin_amdgcn_mfma_f32_16x16x32_bf16(a0, b, acc[0][t], 0, 0, 0);
            acc[1][t] = __builtin_amdgcn_mfma_f32_16x16x32_bf16(a1, b, acc[1][t], 0, 0, 0);
        }
    }

    // C/D layout: col = lane&15, row = (lane>>4)*4 + reg
#pragma unroll
    for (int rt = 0; rt < 2; ++rt)
#pragma unroll
        for (int r = 0; r < 4; ++r) {
            int row = row0 + wave * 32 + rt * 16 + (lane >> 4) * 4 + r;
            if (row < nrows) {
                float dv = dinv[row];
#pragma unroll
                for (int t = 0; t < NT; ++t)
                    Y[(size_t)row * DOUT + t * 16 + (lane & 15)] = f2bf(acc[rt][t][r] * dv);
            }
        }
}

// ---------------- aggregation D=128: LDS-staged neighbor list, decoupled gathers ----------------
// Processes nodes [n0, n1) -- launched as two half-range dispatches (diagnostic).
__global__ __launch_bounds__(256) void agg128_bf16(const unsigned short* __restrict__ Xp,
                                                   const int* __restrict__ csr,
                                                   const int2* __restrict__ offs2,
                                                   const float* __restrict__ dinv,
                                                   const float* __restrict__ bias,
                                                   unsigned short* __restrict__ Y,
                                                   int n0, int n1) {
    __shared__ int sIdx[4][64];
    int wv = threadIdx.x >> 6;
    int node = n0 + blockIdx.x * 4 + wv;
    if (node >= n1) return;
    int lane = threadIdx.x & 63;
    int q = lane >> 4;
    int l = lane & 15;
    int2 se = offs2[node];
    int s = se.x, deg = se.y - se.x;
    if (lane < deg) sIdx[wv][lane] = csr[s + lane];
    int dcap = min(deg, 64);
    const int* idx = sIdx[wv];   // same-wave LDS: program-ordered, no barrier
    f32x2 a0 = {0.f, 0.f}, a1 = {0.f, 0.f}, a2 = {0.f, 0.f}, a3 = {0.f, 0.f};
    int j = q;
    for (; j + 12 < dcap; j += 16) {  // 4 gathers in flight per quarter-wave
        int s0 = idx[j], s1 = idx[j + 4], s2 = idx[j + 8], s3 = idx[j + 12];
        uint4 u0 = *(const uint4*)(Xp + (size_t)s0 * 128 + l * 8);
        uint4 u1 = *(const uint4*)(Xp + (size_t)s1 * 128 + l * 8);
        uint4 u2 = *(const uint4*)(Xp + (size_t)s2 * 128 + l * 8);
        uint4 u3 = *(const uint4*)(Xp + (size_t)s3 * 128 + l * 8);
        a0 += bf2f2(u0.x); a1 += bf2f2(u0.y); a2 += bf2f2(u0.z); a3 += bf2f2(u0.w);
        a0 += bf2f2(u1.x); a1 += bf2f2(u1.y); a2 += bf2f2(u1.z); a3 += bf2f2(u1.w);
        a0 += bf2f2(u2.x); a1 += bf2f2(u2.y); a2 += bf2f2(u2.z); a3 += bf2f2(u2.w);
        a0 += bf2f2(u3.x); a1 += bf2f2(u3.y); a2 += bf2f2(u3.z); a3 += bf2f2(u3.w);
    }
    for (; j < dcap; j += 4) {
        int s0 = idx[j];
        uint4 u = *(const uint4*)(Xp + (size_t)s0 * 128 + l * 8);
        a0 += bf2f2(u.x); a1 += bf2f2(u.y); a2 += bf2f2(u.z); a3 += bf2f2(u.w);
    }
    for (int p = s + 64 + q; p < s + deg; p += 4) {  // deg>64 safety net
        int s0 = csr[p];
        uint4 u = *(const uint4*)(Xp + (size_t)s0 * 128 + l * 8);
        a0 += bf2f2(u.x); a1 += bf2f2(u.y); a2 += bf2f2(u.z); a3 += bf2f2(u.w);
    }
    if (q == 0) {  // self-loop row (prescaled)
        uint4 u = *(const uint4*)(Xp + (size_t)node * 128 + l * 8);
        a0 += bf2f2(u.x); a1 += bf2f2(u.y); a2 += bf2f2(u.z); a3 += bf2f2(u.w);
    }
    float r0 = a0.x, r1 = a0.y, r2 = a1.x, r3 = a1.y;
    float r4 = a2.x, r5 = a2.y, r6 = a3.x, r7 = a3.y;
    r0 += __shfl_xor(r0, 16); r0 += __shfl_xor(r0, 32);
    r1 += __shfl_xor(r1, 16); r1 += __shfl_xor(r1, 32);
    r2 += __shfl_xor(r2, 16); r2 += __shfl_xor(r2, 32);
    r3 += __shfl_xor(r3, 16); r3 += __shfl_xor(r3, 32);
    r4 += __shfl_xor(r4, 16); r4 += __shfl_xor(r4, 32);
    r5 += __shfl_xor(r5, 16); r5 += __shfl_xor(r5, 32);
    r6 += __shfl_xor(r6, 16); r6 += __shfl_xor(r6, 32);
    r7 += __shfl_xor(r7, 16); r7 += __shfl_xor(r7, 32);
    if (q == 0) {
        float di = dinv[node];
        float4 bA = *(const float4*)(bias + l * 8);
        float4 bB = *(const float4*)(bias + l * 8 + 4);
        r0 = fmaxf(fmaf(di, r0, bA.x), 0.f); r1 = fmaxf(fmaf(di, r1, bA.y), 0.f);
        r2 = fmaxf(fmaf(di, r2, bA.z), 0.f); r3 = fmaxf(fmaf(di, r3, bA.w), 0.f);
        r4 = fmaxf(fmaf(di, r4, bB.x), 0.f); r5 = fmaxf(fmaf(di, r5, bB.y), 0.f);
        r6 = fmaxf(fmaf(di, r6, bB.z), 0.f); r7 = fmaxf(fmaf(di, r7, bB.w), 0.f);
        uint4 o;
        o.x = pack2bf(r0, r1); o.y = pack2bf(r2, r3);
        o.z = pack2bf(r4, r5); o.w = pack2bf(r6, r7);
        *(uint4*)(Y + (size_t)node * 128 + l * 8) = o;
    }
}

// ---------------- last layer D=64: LDS-staged list, eighth-wave per edge + log_softmax ----------------
__global__ __launch_bounds__(256) void agg_softmax64_bf16(const unsigned short* __restrict__ Xp,
                                                          const int* __restrict__ csr,
                                                          const int2* __restrict__ offs2,
                                                          const float* __restrict__ dinv,
                                                          const float* __restrict__ bias,
                                                          float* __restrict__ out, int n) {
    __shared__ int sIdx[4][64];
    int wv = threadIdx.x >> 6;
    int node = blockIdx.x * 4 + wv;
    if (node >= n) return;
    int lane = threadIdx.x & 63;
    int g8 = lane >> 3;
    int l = lane & 7;
    int2 se = offs2[node];
    int s = se.x, deg = se.y - se.x;
    if (lane < deg) sIdx[wv][lane] = csr[s + lane];
    int dcap = min(deg, 64);
    const int* idx = sIdx[wv];
    f32x2 a0 = {0.f, 0.f}, a1 = {0.f, 0.f}, a2 = {0.f, 0.f}, a3 = {0.f, 0.f};
    int j = g8;
    for (; j + 8 < dcap; j += 16) {
        int s0 = idx[j], s1 = idx[j + 8];
        uint4 u0 = *(const uint4*)(Xp + (size_t)s0 * 64 + l * 8);
        uint4 u1 = *(const uint4*)(Xp + (size_t)s1 * 64 + l * 8);
        a0 += bf2f2(u0.x); a1 += bf2f2(u0.y); a2 += bf2f2(u0.z); a3 += bf2f2(u0.w);
        a0 += bf2f2(u1.x); a1 += bf2f2(u1.y); a2 += bf2f2(u1.z); a3 += bf2f2(u1.w);
    }
    if (j < dcap) {
        int s0 = idx[j];
        uint4 u = *(const uint4*)(Xp + (size_t)s0 * 64 + l * 8);
        a0 += bf2f2(u.x); a1 += bf2f2(u.y); a2 += bf2f2(u.z); a3 += bf2f2(u.w);
    }
    for (int p = s + 64 + g8; p < s + deg; p += 8) {  // deg>64 safety net
        int s0 = csr[p];
        uint4 u = *(const uint4*)(Xp + (size_t)s0 * 64 + l * 8);
        a0 += bf2f2(u.x); a1 += bf2f2(u.y); a2 += bf2f2(u.z); a3 += bf2f2(u.w);
    }
    if (g8 == 0) {  // self-loop
        uint4 u = *(const uint4*)(Xp + (size_t)node * 64 + l * 8);
        a0 += bf2f2(u.x); a1 += bf2f2(u.y); a2 += bf2f2(u.z); a3 += bf2f2(u.w);
    }
    float r0 = a0.x, r1 = a0.y, r2 = a1.x, r3 = a1.y;
    float r4 = a2.x, r5 = a2.y, r6 = a3.x, r7 = a3.y;
    r0 += __shfl_xor(r0, 8); r0 += __shfl_xor(r0, 16); r0 += __shfl_xor(r0, 32);
    r1 += __shfl_xor(r1, 8); r1 += __shfl_xor(r1, 16); r1 += __shfl_xor(r1, 32);
    r2 += __shfl_xor(r2, 8); r2 += __shfl_xor(r2, 16); r2 += __shfl_xor(r2, 32);
    r3 += __shfl_xor(r3, 8); r3 += __shfl_xor(r3, 16); r3 += __shfl_xor(r3, 32);
    r4 += __shfl_xor(r4, 8); r4 += __shfl_xor(r4, 16); r4 += __shfl_xor(r4, 32);
    r5 += __shfl_xor(r5, 8); r5 += __shfl_xor(r5, 16); r5 += __shfl_xor(r5, 32);
    r6 += __shfl_xor(r6, 8); r6 += __shfl_xor(r6, 16); r6 += __shfl_xor(r6, 32);
    r7 += __shfl_xor(r7, 8); r7 += __shfl_xor(r7, 16); r7 += __shfl_xor(r7, 32);
    if (g8 == 0) {
        float di = dinv[node];
        float4 bA = *(const float4*)(bias + l * 8);
        float4 bB = *(const float4*)(bias + l * 8 + 4);
        r0 = fmaf(di, r0, bA.x); r1 = fmaf(di, r1, bA.y);
        r2 = fmaf(di, r2, bA.z); r3 = fmaf(di, r3, bA.w);
        r4 = fmaf(di, r4, bB.x); r5 = fmaf(di, r5, bB.y);
        r6 = fmaf(di, r6, bB.z); r7 = fmaf(di, r7, bB.w);
        float m = fmaxf(fmaxf(fmaxf(r0, r1), fmaxf(r2, r3)), fmaxf(fmaxf(r4, r5), fmaxf(r6, r7)));
#pragma unroll
        for (int o = 4; o > 0; o >>= 1) m = fmaxf(m, __shfl_xor(m, o));
        float ssum = __expf(r0 - m) + __expf(r1 - m) + __expf(r2 - m) + __expf(r3 - m) +
                     __expf(r4 - m) + __expf(r5 - m) + __expf(r6 - m) + __expf(r7 - m);
#pragma unroll
        for (int o = 4; o > 0; o >>= 1) ssum += __shfl_xor(ssum, o);
        float lg = m + __logf(ssum);
        float4 o0 = make_float4(r0 - lg, r1 - lg, r2 - lg, r3 - lg);
        float4 o1 = make_float4(r4 - lg, r5 - lg, r6 - lg, r7 - lg);
        *(float4*)(out + (size_t)node * 64 + l * 8) = o0;
        *(float4*)(out + (size_t)node * 64 + l * 8 + 4) = o1;
    }
}

// ---------------- launcher ----------------

extern "C" void kernel_launch(void* const* d_in, const int* in_sizes, int n_in,
                              void* d_out, int out_size, void* d_ws, size_t ws_size,
                              hipStream_t stream) {
    const int* edges = (const int*)d_in[0];
    const float* feat = (const float*)d_in[1];
    const float* W0 = (const float*)d_in[2];
    const float* b0 = (const float*)d_in[3];
    const float* W1 = (const float*)d_in[4];
    const float* b1 = (const float*)d_in[5];
    const float* W2 = (const float*)d_in[6];
    const float* b2 = (const float*)d_in[7];

    const int N = NN;
    const int E = EE;

    char* ws = (char*)d_ws;
    int* bcount = (int*)ws;                       // NB2
    int2* offs2 = (int2*)(bcount + ((NB2 + 1) & ~1));  // N (8B aligned)
    float* dinv = (float*)(offs2 + N);            // N
    int* P = (int*)(dinv + N);                    // NB2*CAP (packed src<<7|dst&127)
    int* csr = P + (size_t)NB2 * CAP;             // NB2*CAP (src only)
    unsigned short* Wt0 = (unsigned short*)(csr + (size_t)NB2 * CAP);  // 16384
    unsigned short* Wt1 = Wt0 + 16384;            // 16384
    unsigned short* Wt2 = Wt1 + 16384;            // 8192
    size_t off = (size_t)((char*)(Wt2 + 8192) - ws);
    off = (off + 255) & ~(size_t)255;
    unsigned short* bufA = (unsigned short*)(ws + off);  // N*128 bf16
    unsigned short* bufB = bufA + (size_t)N * 128;       // N*128 bf16

    const int* esrc = edges;
    const int* edst = edges + E;

    // CSR build
    prep_weights<<<160, 256, 0, stream>>>(W0, W1, W2, Wt0, Wt1, Wt2, bcount);
    scatter_bump<<<NPART, 256, 0, stream>>>(esrc, edst, bcount, P, E);
    bucket_build<<<NB2, 256, 0, stream>>>(P, bcount, offs2, dinv, csr, N);

    const int gemmBlocks = (N + 127) / 128;  // 782
    const int NH = N / 2;                    // 50000
    const int halfBlocks = (NH + 3) / 4;     // 12500
    const int aggBlocks = (N + 3) / 4;       // 25000

    // layer 0
    gemm_mfma<128, true><<<gemmBlocks, 256, 0, stream>>>(feat, Wt0, dinv, bufA, N);
    agg128_bf16<<<halfBlocks, 256, 0, stream>>>(bufA, csr, offs2, dinv, b0, bufB, 0, NH);
    agg128_bf16<<<halfBlocks, 256, 0, stream>>>(bufA, csr, offs2, dinv, b0, bufB, NH, N);
    // layer 1
    gemm_mfma<128, false><<<gemmBlocks, 256, 0, stream>>>(bufB, Wt1, dinv, bufA, N);
    agg128_bf16<<<halfBlocks, 256, 0, stream>>>(bufA, csr, offs2, dinv, b1, bufB, 0, NH);
    agg128_bf16<<<halfBlocks, 256, 0, stream>>>(bufA, csr, offs2, dinv, b1, bufB, NH, N);
    // layer 2 + log_softmax
    gemm_mfma<64, false><<<gemmBlocks, 256, 0, stream>>>(bufB, Wt2, dinv, bufA, N);
    agg_softmax64_bf16<<<aggBlocks, 256, 0, stream>>>(bufA, csr, offs2, dinv, b2, (float*)d_out, N);
}

// Round 15
// 392.410 us; speedup vs baseline: 1.0332x; 1.0332x over previous
//
#include <hip/hip_runtime.h>
#include <hip/hip_fp16.h>
#include <math.h>

// StackedGCN: N=100000, E=1600000, 128 -> 128 -> 128 -> 64, fp32 in/out.
// FP16 activation pipeline (finer than bf16), fp32 MFMA accumulation,
// dinv prescaled in GEMM epilogue (aggregation = pure sum of rows).
// Aggregation inner loops accumulate with packed v_pk_add_f16 (1 inst per
// 2 features vs 3 for unpack+f32-add) using dual accumulator sets (chain
// depth ~2-4), converted to f32 before cross-lane reduction + epilogue.
// CSR build: single-kernel bump allocation into padded bucket segments +
// LDS counting sort (no scattered global stores anywhere).
#define NN 100000
#define EE 1600000
#define NB2 782     // dst buckets: dst>>7 -> 128 nodes per bucket
#define BN 128      // nodes per bucket
#define NPART 512   // scatter_bump blocks
#define CAP 2560    // padded segment capacity (mean 2048, sd ~45 -> +11 sigma)

typedef __attribute__((ext_vector_type(8))) _Float16 half8;
typedef __attribute__((ext_vector_type(4))) float f32x4;

__device__ inline unsigned short f2h(float x) {
    return __half_as_ushort(__float2half(x));
}
__device__ inline __half2 u2h2(unsigned u) {
    return __builtin_bit_cast(__half2, u);
}
__device__ inline unsigned h22u(__half2 h) {
    return __builtin_bit_cast(unsigned, h);
}

// ---------------- weight prep (+ bcount zero) ----------------

__global__ void prep_weights(const float* __restrict__ W0, const float* __restrict__ W1,
                             const float* __restrict__ W2, unsigned short* __restrict__ Wt0,
                             unsigned short* __restrict__ Wt1, unsigned short* __restrict__ Wt2,
                             int* __restrict__ bcount) {
    int g = blockIdx.x * 256 + threadIdx.x;
    if (g < NB2) bcount[g] = 0;
    if (g < 16384) {
        int n = g >> 7, k = g & 127;
        Wt0[g] = f2h(W0[k * 128 + n]);
    } else if (g < 32768) {
        int i = g - 16384;
        int n = i >> 7, k = i & 127;
        Wt1[i] = f2h(W1[k * 128 + n]);
    } else if (g < 40960) {
        int i = g - 32768;
        int n = i >> 7, k = i & 127;
        Wt2[i] = f2h(W2[k * 64 + n]);
    }
}

// ---------------- CSR build ----------------

__global__ __launch_bounds__(256) void scatter_bump(const int* __restrict__ src,
                                                    const int* __restrict__ dst,
                                                    int* __restrict__ bcount,
                                                    int* __restrict__ P, int e) {
    __shared__ int cnt[NB2];
    __shared__ int basep[NB2];
    __shared__ int cur[NB2];
    int t = threadIdx.x;
    for (int i = t; i < NB2; i += 256) { cnt[i] = 0; cur[i] = 0; }
    __syncthreads();
    int chunk = (e + NPART - 1) / NPART;
    int b0 = blockIdx.x * chunk, b1 = min(e, b0 + chunk);
    for (int i = b0 + t; i < b1; i += 256)
        atomicAdd(&cnt[dst[i] >> 7], 1);
    __syncthreads();
    for (int i = t; i < NB2; i += 256) {
        int c = cnt[i];
        basep[i] = c ? atomicAdd(&bcount[i], c) : 0;
    }
    __syncthreads();
    for (int i = b0 + t; i < b1; i += 256) {  // second read is L2-hot
        int d = dst[i];
        int b = d >> 7;
        int p = basep[b] + atomicAdd(&cur[b], 1);
        P[(size_t)b * CAP + p] = (src[i] << 7) | (d & 127);  // src<2^17: 24 bits
    }
}

__global__ __launch_bounds__(256) void bucket_build(const int* __restrict__ P,
                                                    const int* __restrict__ bcount,
                                                    int2* __restrict__ offs2,
                                                    float* __restrict__ dinv,
                                                    int* __restrict__ csr, int n) {
    __shared__ int cnt[BN];
    __shared__ int sc[BN];
    __shared__ int cur[BN];
    __shared__ int stage[CAP];
    int b = blockIdx.x, t = threadIdx.x;
    int base = b * CAP;
    int count = bcount[b];
    if (t < BN) cnt[t] = 0;
    __syncthreads();
    for (int i = t; i < count; i += 256)
        atomicAdd(&cnt[P[base + i] & 127], 1);
    __syncthreads();
    int v = 0;
    if (t < BN) {
        v = cnt[t];
        sc[t] = v;
    }
    for (int d = 1; d < BN; d <<= 1) {
        __syncthreads();
        int x = (t < BN && t >= d) ? sc[t - d] : 0;
        __syncthreads();
        if (t < BN) sc[t] += x;
    }
    __syncthreads();
    if (t < BN) {
        int myoff = sc[t] - v;
        int node = b * BN + t;
        if (node < n) {
            offs2[node] = make_int2(base + myoff, base + myoff + v);
            dinv[node] = 1.0f / sqrtf((float)(v + 1));  // +1 self-loop
        }
        cur[t] = myoff;
    }
    __syncthreads();
    for (int i = t; i < count; i += 256) {  // second read L2-hot
        int pe = P[base + i];
        int p = atomicAdd(&cur[pe & 127], 1);
        stage[p] = ((unsigned)pe) >> 7;     // p < count <= CAP always
    }
    __syncthreads();
    for (int i = t; i < count; i += 256) csr[base + i] = stage[i];
}

// ---------------- MFMA GEMM (f16) + dinv-prescale epilogue ----------------
template <int DOUT, bool A_IS_F32>
__global__ __launch_bounds__(256) void gemm_mfma(const void* __restrict__ Aptr,
                                                 const unsigned short* __restrict__ Wt,
                                                 const float* __restrict__ dinv,
                                                 unsigned short* __restrict__ Y, int nrows) {
    constexpr int KP = 136;
    constexpr int NT = DOUT / 16;
    __shared__ unsigned short sA[128 * KP];
    __shared__ unsigned short sB[DOUT * KP];
    const int row0 = blockIdx.x * 128;
    const int tid = threadIdx.x;

    for (int i = tid; i < DOUT * 16; i += 256) {
        int n = i >> 4, c = (i & 15) * 8;
        uint4 v = *(const uint4*)(Wt + n * 128 + c);
        *(uint4*)(&sB[n * KP + c]) = v;
    }
    if (A_IS_F32) {
        const float* A = (const float*)Aptr;
        for (int i = tid; i < 128 * 32; i += 256) {
            int r = i >> 5, c = (i & 31) * 4;
            float4 v = make_float4(0.f, 0.f, 0.f, 0.f);
            if (row0 + r < nrows) v = *(const float4*)(A + (size_t)(row0 + r) * 128 + c);
            uint2 o;
            o.x = h22u(__floats2half2_rn(v.x, v.y));
            o.y = h22u(__floats2half2_rn(v.z, v.w));
            *(uint2*)(&sA[r * KP + c]) = o;
        }
    } else {
        const unsigned short* A = (const unsigned short*)Aptr;
        for (int i = tid; i < 128 * 16; i += 256) {
            int r = i >> 4, c = (i & 15) * 8;
            uint4 v = make_uint4(0u, 0u, 0u, 0u);
            if (row0 + r < nrows) v = *(const uint4*)(A + (size_t)(row0 + r) * 128 + c);
            *(uint4*)(&sA[r * KP + c]) = v;
        }
    }
    __syncthreads();

    const int wave = tid >> 6;
    const int lane = tid & 63;
    const int m0 = lane & 15;
    const int kq = (lane >> 4) * 8;

    f32x4 acc[2][NT];
#pragma unroll
    for (int rt = 0; rt < 2; ++rt)
#pragma unroll
        for (int t = 0; t < NT; ++t) acc[rt][t] = (f32x4){0.f, 0.f, 0.f, 0.f};

#pragma unroll
    for (int k0 = 0; k0 < 128; k0 += 32) {
        half8 a0 = *(const half8*)(&sA[(wave * 32 + m0) * KP + k0 + kq]);
        half8 a1 = *(const half8*)(&sA[(wave * 32 + 16 + m0) * KP + k0 + kq]);
#pragma unroll
        for (int t = 0; t < NT; ++t) {
            half8 b = *(const half8*)(&sB[(t * 16 + m0) * KP + k0 + kq]);
            acc[0][t] = __builtin_amdgcn_mfma_f32_16x16x32_f16(a0, b, acc[0][t], 0, 0, 0);
            acc[1][t] = __builtin_amdgcn_mfma_f32_16x16x32_f16(a1, b, acc[1][t], 0, 0, 0);
        }
    }

    // C/D layout: col = lane&15, row = (lane>>4)*4 + reg (dtype-independent)
#pragma unroll
    for (int rt = 0; rt < 2; ++rt)
#pragma unroll
        for (int r = 0; r < 4; ++r) {
            int row = row0 + wave * 32 + rt * 16 + (lane >> 4) * 4 + r;
            if (row < nrows) {
                float dv = dinv[row];
#pragma unroll
                for (int t = 0; t < NT; ++t)
                    Y[(size_t)row * DOUT + t * 16 + (lane & 15)] = f2h(acc[rt][t][r] * dv);
            }
        }
}

// ---------------- aggregation D=128: LDS-staged list, packed fp16 accumulation ----------------
__global__ __launch_bounds__(256) void agg128_f16(const unsigned short* __restrict__ Xp,
                                                  const int* __restrict__ csr,
                                                  const int2* __restrict__ offs2,
                                                  const float* __restrict__ dinv,
                                                  const float* __restrict__ bias,
                                                  unsigned short* __restrict__ Y, int n) {
    __shared__ int sIdx[4][64];
    int wv = threadIdx.x >> 6;
    int node = blockIdx.x * 4 + wv;
    if (node >= n) return;
    int lane = threadIdx.x & 63;
    int q = lane >> 4;
    int l = lane & 15;
    int2 se = offs2[node];
    int s = se.x, deg = se.y - se.x;
    if (lane < deg) sIdx[wv][lane] = csr[s + lane];
    int dcap = min(deg, 64);
    const int* idx = sIdx[wv];   // same-wave LDS: program-ordered, no barrier
    const __half2 hz = __floats2half2_rn(0.f, 0.f);
    __half2 aA0 = hz, aA1 = hz, aA2 = hz, aA3 = hz;   // set A: edges j, j+8
    __half2 aB0 = hz, aB1 = hz, aB2 = hz, aB3 = hz;   // set B: edges j+4, j+12
    int j = q;
    for (; j + 12 < dcap; j += 16) {  // 4 gathers in flight per quarter-wave
        int s0 = idx[j], s1 = idx[j + 4], s2 = idx[j + 8], s3 = idx[j + 12];
        uint4 u0 = *(const uint4*)(Xp + (size_t)s0 * 128 + l * 8);
        uint4 u1 = *(const uint4*)(Xp + (size_t)s1 * 128 + l * 8);
        uint4 u2 = *(const uint4*)(Xp + (size_t)s2 * 128 + l * 8);
        uint4 u3 = *(const uint4*)(Xp + (size_t)s3 * 128 + l * 8);
        aA0 = __hadd2(aA0, u2h2(u0.x)); aA1 = __hadd2(aA1, u2h2(u0.y));
        aA2 = __hadd2(aA2, u2h2(u0.z)); aA3 = __hadd2(aA3, u2h2(u0.w));
        aB0 = __hadd2(aB0, u2h2(u1.x)); aB1 = __hadd2(aB1, u2h2(u1.y));
        aB2 = __hadd2(aB2, u2h2(u1.z)); aB3 = __hadd2(aB3, u2h2(u1.w));
        aA0 = __hadd2(aA0, u2h2(u2.x)); aA1 = __hadd2(aA1, u2h2(u2.y));
        aA2 = __hadd2(aA2, u2h2(u2.z)); aA3 = __hadd2(aA3, u2h2(u2.w));
        aB0 = __hadd2(aB0, u2h2(u3.x)); aB1 = __hadd2(aB1, u2h2(u3.y));
        aB2 = __hadd2(aB2, u2h2(u3.z)); aB3 = __hadd2(aB3, u2h2(u3.w));
    }
    for (; j < dcap; j += 4) {
        int s0 = idx[j];
        uint4 u = *(const uint4*)(Xp + (size_t)s0 * 128 + l * 8);
        aA0 = __hadd2(aA0, u2h2(u.x)); aA1 = __hadd2(aA1, u2h2(u.y));
        aA2 = __hadd2(aA2, u2h2(u.z)); aA3 = __hadd2(aA3, u2h2(u.w));
    }
    for (int p = s + 64 + q; p < s + deg; p += 4) {  // deg>64 safety net
        int s0 = csr[p];
        uint4 u = *(const uint4*)(Xp + (size_t)s0 * 128 + l * 8);
        aB0 = __hadd2(aB0, u2h2(u.x)); aB1 = __hadd2(aB1, u2h2(u.y));
        aB2 = __hadd2(aB2, u2h2(u.z)); aB3 = __hadd2(aB3, u2h2(u.w));
    }
    if (q == 0) {  // self-loop row (prescaled)
        uint4 u = *(const uint4*)(Xp + (size_t)node * 128 + l * 8);
        aB0 = __hadd2(aB0, u2h2(u.x)); aB1 = __hadd2(aB1, u2h2(u.y));
        aB2 = __hadd2(aB2, u2h2(u.z)); aB3 = __hadd2(aB3, u2h2(u.w));
    }
    // combine sets in f32, then cross-lane reduce in f32
    float2 fA, fB;
    fA = __half22float2(aA0); fB = __half22float2(aB0);
    float r0 = fA.x + fB.x, r1 = fA.y + fB.y;
    fA = __half22float2(aA1); fB = __half22float2(aB1);
    float r2 = fA.x + fB.x, r3 = fA.y + fB.y;
    fA = __half22float2(aA2); fB = __half22float2(aB2);
    float r4 = fA.x + fB.x, r5 = fA.y + fB.y;
    fA = __half22float2(aA3); fB = __half22float2(aB3);
    float r6 = fA.x + fB.x, r7 = fA.y + fB.y;
    r0 += __shfl_xor(r0, 16); r0 += __shfl_xor(r0, 32);
    r1 += __shfl_xor(r1, 16); r1 += __shfl_xor(r1, 32);
    r2 += __shfl_xor(r2, 16); r2 += __shfl_xor(r2, 32);
    r3 += __shfl_xor(r3, 16); r3 += __shfl_xor(r3, 32);
    r4 += __shfl_xor(r4, 16); r4 += __shfl_xor(r4, 32);
    r5 += __shfl_xor(r5, 16); r5 += __shfl_xor(r5, 32);
    r6 += __shfl_xor(r6, 16); r6 += __shfl_xor(r6, 32);
    r7 += __shfl_xor(r7, 16); r7 += __shfl_xor(r7, 32);
    if (q == 0) {
        float di = dinv[node];
        float4 bA = *(const float4*)(bias + l * 8);
        float4 bB = *(const float4*)(bias + l * 8 + 4);
        r0 = fmaxf(fmaf(di, r0, bA.x), 0.f); r1 = fmaxf(fmaf(di, r1, bA.y), 0.f);
        r2 = fmaxf(fmaf(di, r2, bA.z), 0.f); r3 = fmaxf(fmaf(di, r3, bA.w), 0.f);
        r4 = fmaxf(fmaf(di, r4, bB.x), 0.f); r5 = fmaxf(fmaf(di, r5, bB.y), 0.f);
        r6 = fmaxf(fmaf(di, r6, bB.z), 0.f); r7 = fmaxf(fmaf(di, r7, bB.w), 0.f);
        uint4 o;
        o.x = h22u(__floats2half2_rn(r0, r1));
        o.y = h22u(__floats2half2_rn(r2, r3));
        o.z = h22u(__floats2half2_rn(r4, r5));
        o.w = h22u(__floats2half2_rn(r6, r7));
        *(uint4*)(Y + (size_t)node * 128 + l * 8) = o;
    }
}

// ---------------- last layer D=64: packed fp16 accumulation + log_softmax ----------------
__global__ __launch_bounds__(256) void agg_softmax64_f16(const unsigned short* __restrict__ Xp,
                                                         const int* __restrict__ csr,
                                                         const int2* __restrict__ offs2,
                                                         const float* __restrict__ dinv,
                                                         const float* __restrict__ bias,
                                                         float* __restrict__ out, int n) {
    __shared__ int sIdx[4][64];
    int wv = threadIdx.x >> 6;
    int node = blockIdx.x * 4 + wv;
    if (node >= n) return;
    int lane = threadIdx.x & 63;
    int g8 = lane >> 3;
    int l = lane & 7;
    int2 se = offs2[node];
    int s = se.x, deg = se.y - se.x;
    if (lane < deg) sIdx[wv][lane] = csr[s + lane];
    int dcap = min(deg, 64);
    const int* idx = sIdx[wv];
    const __half2 hz = __floats2half2_rn(0.f, 0.f);
    __half2 aA0 = hz, aA1 = hz, aA2 = hz, aA3 = hz;
    __half2 aB0 = hz, aB1 = hz, aB2 = hz, aB3 = hz;
    int j = g8;
    for (; j + 8 < dcap; j += 16) {
        int s0 = idx[j], s1 = idx[j + 8];
        uint4 u0 = *(const uint4*)(Xp + (size_t)s0 * 64 + l * 8);
        uint4 u1 = *(const uint4*)(Xp + (size_t)s1 * 64 + l * 8);
        aA0 = __hadd2(aA0, u2h2(u0.x)); aA1 = __hadd2(aA1, u2h2(u0.y));
        aA2 = __hadd2(aA2, u2h2(u0.z)); aA3 = __hadd2(aA3, u2h2(u0.w));
        aB0 = __hadd2(aB0, u2h2(u1.x)); aB1 = __hadd2(aB1, u2h2(u1.y));
        aB2 = __hadd2(aB2, u2h2(u1.z)); aB3 = __hadd2(aB3, u2h2(u1.w));
    }
    if (j < dcap) {
        int s0 = idx[j];
        uint4 u = *(const uint4*)(Xp + (size_t)s0 * 64 + l * 8);
        aA0 = __hadd2(aA0, u2h2(u.x)); aA1 = __hadd2(aA1, u2h2(u.y));
        aA2 = __hadd2(aA2, u2h2(u.z)); aA3 = __hadd2(aA3, u2h2(u.w));
    }
    for (int p = s + 64 + g8; p < s + deg; p += 8) {  // deg>64 safety net
        int s0 = csr[p];
        uint4 u = *(const uint4*)(Xp + (size_t)s0 * 64 + l * 8);
        aB0 = __hadd2(aB0, u2h2(u.x)); aB1 = __hadd2(aB1, u2h2(u.y));
        aB2 = __hadd2(aB2, u2h2(u.z)); aB3 = __hadd2(aB3, u2h2(u.w));
    }
    if (g8 == 0) {  // self-loop
        uint4 u = *(const uint4*)(Xp + (size_t)node * 64 + l * 8);
        aB0 = __hadd2(aB0, u2h2(u.x)); aB1 = __hadd2(aB1, u2h2(u.y));
        aB2 = __hadd2(aB2, u2h2(u.z)); aB3 = __hadd2(aB3, u2h2(u.w));
    }
    float2 fA, fB;
    fA = __half22float2(aA0); fB = __half22float2(aB0);
    float r0 = fA.x + fB.x, r1 = fA.y + fB.y;
    fA = __half22float2(aA1); fB = __half22float2(aB1);
    float r2 = fA.x + fB.x, r3 = fA.y + fB.y;
    fA = __half22float2(aA2); fB = __half22float2(aB2);
    float r4 = fA.x + fB.x, r5 = fA.y + fB.y;
    fA = __half22float2(aA3); fB = __half22float2(aB3);
    float r6 = fA.x + fB.x, r7 = fA.y + fB.y;
    r0 += __shfl_xor(r0, 8); r0 += __shfl_xor(r0, 16); r0 += __shfl_xor(r0, 32);
    r1 += __shfl_xor(r1, 8); r1 += __shfl_xor(r1, 16); r1 += __shfl_xor(r1, 32);
    r2 += __shfl_xor(r2, 8); r2 += __shfl_xor(r2, 16); r2 += __shfl_xor(r2, 32);
    r3 += __shfl_xor(r3, 8); r3 += __shfl_xor(r3, 16); r3 += __shfl_xor(r3, 32);
    r4 += __shfl_xor(r4, 8); r4 += __shfl_xor(r4, 16); r4 += __shfl_xor(r4, 32);
    r5 += __shfl_xor(r5, 8); r5 += __shfl_xor(r5, 16); r5 += __shfl_xor(r5, 32);
    r6 += __shfl_xor(r6, 8); r6 += __shfl_xor(r6, 16); r6 += __shfl_xor(r6, 32);
    r7 += __shfl_xor(r7, 8); r7 += __shfl_xor(r7, 16); r7 += __shfl_xor(r7, 32);
    if (g8 == 0) {
        float di = dinv[node];
        float4 bA = *(const float4*)(bias + l * 8);
        float4 bB = *(const float4*)(bias + l * 8 + 4);
        r0 = fmaf(di, r0, bA.x); r1 = fmaf(di, r1, bA.y);
        r2 = fmaf(di, r2, bA.z); r3 = fmaf(di, r3, bA.w);
        r4 = fmaf(di, r4, bB.x); r5 = fmaf(di, r5, bB.y);
        r6 = fmaf(di, r6, bB.z); r7 = fmaf(di, r7, bB.w);
        float m = fmaxf(fmaxf(fmaxf(r0, r1), fmaxf(r2, r3)), fmaxf(fmaxf(r4, r5), fmaxf(r6, r7)));
#pragma unroll
        for (int o = 4; o > 0; o >>= 1) m = fmaxf(m, __shfl_xor(m, o));
        float ssum = __expf(r0 - m) + __expf(r1 - m) + __expf(r2 - m) + __expf(r3 - m) +
                     __expf(r4 - m) + __expf(r5 - m) + __expf(r6 - m) + __expf(r7 - m);
#pragma unroll
        for (int o = 4; o > 0; o >>= 1) ssum += __shfl_xor(ssum, o);
        float lg = m + __logf(ssum);
        float4 o0 = make_float4(r0 - lg, r1 - lg, r2 - lg, r3 - lg);
        float4 o1 = make_float4(r4 - lg, r5 - lg, r6 - lg, r7 - lg);
        *(float4*)(out + (size_t)node * 64 + l * 8) = o0;
        *(float4*)(out + (size_t)node * 64 + l * 8 + 4) = o1;
    }
}

// ---------------- launcher ----------------

extern "C" void kernel_launch(void* const* d_in, const int* in_sizes, int n_in,
                              void* d_out, int out_size, void* d_ws, size_t ws_size,
                              hipStream_t stream) {
    const int* edges = (const int*)d_in[0];
    const float* feat = (const float*)d_in[1];
    const float* W0 = (const float*)d_in[2];
    const float* b0 = (const float*)d_in[3];
    const float* W1 = (const float*)d_in[4];
    const float* b1 = (const float*)d_in[5];
    const float* W2 = (const float*)d_in[6];
    const float* b2 = (const float*)d_in[7];

    const int N = NN;
    const int E = EE;

    char* ws = (char*)d_ws;
    int* bcount = (int*)ws;                       // NB2
    int2* offs2 = (int2*)(bcount + ((NB2 + 1) & ~1));  // N (8B aligned)
    float* dinv = (float*)(offs2 + N);            // N
    int* P = (int*)(dinv + N);                    // NB2*CAP (packed src<<7|dst&127)
    int* csr = P + (size_t)NB2 * CAP;             // NB2*CAP (src only)
    unsigned short* Wt0 = (unsigned short*)(csr + (size_t)NB2 * CAP);  // 16384
    unsigned short* Wt1 = Wt0 + 16384;            // 16384
    unsigned short* Wt2 = Wt1 + 16384;            // 8192
    size_t off = (size_t)((char*)(Wt2 + 8192) - ws);
    off = (off + 255) & ~(size_t)255;
    unsigned short* bufA = (unsigned short*)(ws + off);  // N*128 fp16
    unsigned short* bufB = bufA + (size_t)N * 128;       // N*128 fp16

    const int* esrc = edges;
    const int* edst = edges + E;

    // CSR build
    prep_weights<<<160, 256, 0, stream>>>(W0, W1, W2, Wt0, Wt1, Wt2, bcount);
    scatter_bump<<<NPART, 256, 0, stream>>>(esrc, edst, bcount, P, E);
    bucket_build<<<NB2, 256, 0, stream>>>(P, bcount, offs2, dinv, csr, N);

    const int gemmBlocks = (N + 127) / 128;  // 782
    const int aggBlocks = (N + 3) / 4;       // 25000

    // layer 0
    gemm_mfma<128, true><<<gemmBlocks, 256, 0, stream>>>(feat, Wt0, dinv, bufA, N);
    agg128_f16<<<aggBlocks, 256, 0, stream>>>(bufA, csr, offs2, dinv, b0, bufB, N);
    // layer 1
    gemm_mfma<128, false><<<gemmBlocks, 256, 0, stream>>>(bufB, Wt1, dinv, bufA, N);
    agg128_f16<<<aggBlocks, 256, 0, stream>>>(bufA, csr, offs2, dinv, b1, bufB, N);
    // layer 2 + log_softmax
    gemm_mfma<64, false><<<gemmBlocks, 256, 0, stream>>>(bufB, Wt2, dinv, bufA, N);
    agg_softmax64_f16<<<aggBlocks, 256, 0, stream>>>(bufA, csr, offs2, dinv, b2, (float*)d_out, N);
}